// Round 1
// baseline (1106.430 us; speedup 1.0000x reference)
//
#include <hip/hip_runtime.h>
#include <hip/hip_bf16.h>
#include <stdint.h>
#include <math.h>

#define H_ 12
#define NQ 196
#define CD 768
#define HIDD 3072
#define VX 8
#define VY 8
#define BB 4
#define MV 4
#define VBB 32
#define ROWS 6272          // VBB*NQ
#define CROSS_ROWS 25088   // VX*MV*BB*NQ
#define ATT_SCALE 0.125f

typedef __attribute__((ext_vector_type(8))) short short8;
typedef __attribute__((ext_vector_type(4))) float f32x4;
typedef unsigned short u16;

__device__ __forceinline__ float bf2f(u16 u){
  union { unsigned int i; float f; } v; v.i = ((unsigned int)u) << 16; return v.f;
}
__device__ __forceinline__ u16 f2bf(float f){
  union { unsigned int i; float f; } v; v.f = f;
  return (u16)((v.i + 0x7fff + ((v.i >> 16) & 1)) >> 16);  // RNE
}

// ---------------- cast f32 -> bf16 ----------------
__global__ void k_cast_bf16(const float* __restrict__ in, u16* __restrict__ out, int n){
  int i = blockIdx.x * 256 + threadIdx.x;
  if (i < n) out[i] = f2bf(in[i]);
}

// ---------------- LayerNorm (f32 in, bf16 out), C=768 fixed ----------------
__global__ __launch_bounds__(256) void k_ln_bf16(const float* __restrict__ x,
    const float* __restrict__ w, const float* __restrict__ b,
    u16* __restrict__ out){
  const int row = blockIdx.x;
  const int tid = threadIdx.x;
  const float* xr = x + (size_t)row * CD;
  float v0 = xr[tid], v1 = xr[tid + 256], v2 = xr[tid + 512];
  float s  = v0 + v1 + v2;
  float s2 = v0*v0 + v1*v1 + v2*v2;
  __shared__ float red[8];
  const int lane = tid & 63, wid = tid >> 6;
  #pragma unroll
  for (int o = 32; o; o >>= 1){ s += __shfl_down(s, o); s2 += __shfl_down(s2, o); }
  if (lane == 0){ red[wid] = s; red[wid + 4] = s2; }
  __syncthreads();
  if (tid == 0){
    red[0] = red[0] + red[1] + red[2] + red[3];
    red[4] = red[4] + red[5] + red[6] + red[7];
  }
  __syncthreads();
  const float mu   = red[0] * (1.f/768.f);
  const float var  = red[4] * (1.f/768.f) - mu*mu;
  const float rstd = rsqrtf(var + 1e-5f);
  u16* orow = out + (size_t)row * CD;
  orow[tid]       = f2bf((v0 - mu)*rstd*w[tid]       + b[tid]);
  orow[tid + 256] = f2bf((v1 - mu)*rstd*w[tid + 256] + b[tid + 256]);
  orow[tid + 512] = f2bf((v2 - mu)*rstd*w[tid + 512] + b[tid + 512]);
}

// ---------------- bf16 MFMA GEMM: C = A(MxK) @ B(NxK)^T, m97 structure ----------------
// EPI: 0 = plain -> bf16 out; 1 = +bias +resid -> f32; 2 = +bias -> f32; 3 = +bias +GELU -> bf16
template<int EPI>
__global__ __launch_bounds__(256) void k_gemm_bt(
    const u16* __restrict__ A, const u16* __restrict__ B,
    float* __restrict__ Cf, u16* __restrict__ Cb,
    const float* __restrict__ bias, const float* __restrict__ resid,
    int M, int N, int K){
  __shared__ u16 As[128 * 64];
  __shared__ u16 Bs[128 * 64];
  const int tid  = threadIdx.x;
  const int lane = tid & 63;
  const int wave = tid >> 6;
  const int wr = wave >> 1, wc = wave & 1;
  const int m0 = blockIdx.y * 128, n0 = blockIdx.x * 128;

  f32x4 acc[4][4];
  #pragma unroll
  for (int i = 0; i < 4; i++)
    #pragma unroll
    for (int j = 0; j < 4; j++) acc[i][j] = (f32x4){0.f, 0.f, 0.f, 0.f};

  const int lrow = lane >> 3;        // 0..7
  const int lcol = (lane & 7) * 8;   // 0,8,..,56
  const u16* arow = A + (size_t)(m0 + wave*32 + lrow) * K + lcol;
  const u16* brow = B + (size_t)(n0 + wave*32 + lrow) * K + lcol;

  for (int k0 = 0; k0 < K; k0 += 64){
    #pragma unroll
    for (int i = 0; i < 4; i++){
      __builtin_amdgcn_global_load_lds(
        (const __attribute__((address_space(1))) void*)(arow + (size_t)i*8*K + k0),
        (__attribute__((address_space(3))) void*)(As + (wave*4 + i)*512),
        16, 0, 0);
      __builtin_amdgcn_global_load_lds(
        (const __attribute__((address_space(1))) void*)(brow + (size_t)i*8*K + k0),
        (__attribute__((address_space(3))) void*)(Bs + (wave*4 + i)*512),
        16, 0, 0);
    }
    __syncthreads();
    const u16* ab = As + (wr*64 + (lane & 15))*64 + (lane >> 4)*8;
    const u16* bb = Bs + (wc*64 + (lane & 15))*64 + (lane >> 4)*8;
    #pragma unroll
    for (int kk = 0; kk < 2; kk++){
      short8 af[4], bfr[4];
      #pragma unroll
      for (int f = 0; f < 4; f++){
        af[f]  = *(const short8*)(ab + f*1024 + kk*32);
        bfr[f] = *(const short8*)(bb + f*1024 + kk*32);
      }
      #pragma unroll
      for (int i = 0; i < 4; i++)
        #pragma unroll
        for (int j = 0; j < 4; j++)
          acc[i][j] = __builtin_amdgcn_mfma_f32_16x16x32_bf16(af[i], bfr[j], acc[i][j], 0, 0, 0);
    }
    __syncthreads();
  }

  #pragma unroll
  for (int i = 0; i < 4; i++){
    const int rb = m0 + wr*64 + i*16 + (lane >> 4)*4;
    #pragma unroll
    for (int j = 0; j < 4; j++){
      const int col = n0 + wc*64 + j*16 + (lane & 15);
      #pragma unroll
      for (int r = 0; r < 4; r++){
        const size_t idx = (size_t)(rb + r) * N + col;
        const float v = acc[i][j][r];
        if (EPI == 0){
          Cb[idx] = f2bf(v);
        } else if (EPI == 1){
          Cf[idx] = v + bias[col] + resid[idx];
        } else if (EPI == 2){
          Cf[idx] = v + bias[col];
        } else {
          float g = v + bias[col];
          g = 0.5f * g * (1.f + erff(g * 0.70710678118654752f));
          Cb[idx] = f2bf(g);
        }
      }
    }
  }
}

// ---------------- flash attention, one block per head-instance ----------------
// mode 0: self (QKV packed in qkv buffer, row stride 2304)
// mode 1: cross (qs / ks / vs separate, rel_ids gather on K/V)
__global__ __launch_bounds__(256) void k_attn(
    const u16* __restrict__ Qb, const u16* __restrict__ Kb, const u16* __restrict__ Vb,
    u16* __restrict__ Ob, const int* __restrict__ rel_ids, int mode){
  __shared__ float Ks[98 * 64];
  __shared__ float Vs[98 * 64];
  size_t qbase, kbase, vbase, obase;
  int qstr, kstr;
  if (mode == 0){
    const int blk = blockIdx.x;
    const int vb = blk / H_, h = blk % H_;
    qbase = (size_t)vb * NQ * 2304 + h * 64; qstr = 2304;
    kbase = qbase + 768; vbase = qbase + 1536; kstr = 2304;
    obase = (size_t)vb * NQ * CD + h * 64;
  } else {
    const int blk = blockIdx.x;
    const int h = blk % H_; int t = blk / H_;
    const int b = t % BB; t /= BB;
    const int m = t % MV; const int vx = t / MV;
    const int rel = rel_ids[vx * MV + m];
    qbase = ((size_t)(vx * BB + b) * NQ) * CD + h * 64; qstr = CD;
    kbase = ((size_t)(rel * BB + b) * NQ) * CD + h * 64; kstr = CD;
    vbase = kbase;
    obase = ((size_t)((vx * MV + m) * BB + b) * NQ) * CD + h * 64;
  }
  const int tid = threadIdx.x;
  const int q = tid < NQ ? tid : NQ - 1;
  float qv[64], o[64];
  const u16* qp = Qb + qbase + (size_t)q * qstr;
  #pragma unroll
  for (int d = 0; d < 64; d++) qv[d] = bf2f(qp[d]) * ATT_SCALE;
  #pragma unroll
  for (int d = 0; d < 64; d++) o[d] = 0.f;
  float mrun = -1e30f, lrun = 0.f;

  for (int t0 = 0; t0 < NQ; t0 += 98){
    __syncthreads();
    for (int idx = tid; idx < 98 * 64; idx += 256){
      const int j = idx >> 6, d = idx & 63;
      Ks[idx] = bf2f(Kb[kbase + (size_t)(t0 + j) * kstr + d]);
      Vs[idx] = bf2f(Vb[vbase + (size_t)(t0 + j) * kstr + d]);
    }
    __syncthreads();
    for (int j = 0; j < 98; j++){
      const float* kr = Ks + j * 64;
      float s0 = 0.f, s1 = 0.f, s2 = 0.f, s3 = 0.f;
      #pragma unroll
      for (int d = 0; d < 64; d += 4){
        s0 += qv[d]     * kr[d];
        s1 += qv[d + 1] * kr[d + 1];
        s2 += qv[d + 2] * kr[d + 2];
        s3 += qv[d + 3] * kr[d + 3];
      }
      const float s = (s0 + s1) + (s2 + s3);
      const float* vr = Vs + j * 64;
      if (s <= mrun){
        const float p = __expf(s - mrun);
        lrun += p;
        #pragma unroll
        for (int d = 0; d < 64; d++) o[d] += p * vr[d];
      } else {
        const float r = __expf(mrun - s);   // first iter: expf(-huge) -> 0
        lrun = lrun * r + 1.f;
        #pragma unroll
        for (int d = 0; d < 64; d++) o[d] = o[d] * r + vr[d];
        mrun = s;
      }
    }
  }
  if (tid < NQ){
    const float inv = 1.f / lrun;
    u16* op = Ob + obase + (size_t)tid * CD;
    #pragma unroll
    for (int d = 0; d < 64; d++) op[d] = f2bf(o[d] * inv);
  }
}

// ---------------- max over M + residual add ----------------
__global__ void k_maxmerge(const float* __restrict__ op, float* __restrict__ x){
  const int idx = blockIdx.x * 256 + threadIdx.x;
  if (idx >= VX * BB * NQ * CD) return;
  const int inner = idx % (NQ * CD);
  const int vb = idx / (NQ * CD);
  const int vx = vb >> 2, b = vb & 3;
  const size_t ms = (size_t)BB * NQ * CD;
  const size_t base = ((size_t)vx * MV * BB + b) * (NQ * CD) + inner;
  float v = op[base];
  v = fmaxf(v, op[base + ms]);
  v = fmaxf(v, op[base + 2 * ms]);
  v = fmaxf(v, op[base + 3 * ms]);
  x[idx] += v;
}

extern "C" void kernel_launch(void* const* d_in, const int* in_sizes, int n_in,
                              void* d_out, int out_size, void* d_ws, size_t ws_size,
                              hipStream_t stream){
  const float* xs           = (const float*)d_in[0];
  const float* ys           = (const float*)d_in[1];
  const int*   rel_ids      = (const int*)  d_in[4];
  const float* qkv_w        = (const float*)d_in[6];
  const float* attn_proj_w  = (const float*)d_in[7];
  const float* attn_proj_b  = (const float*)d_in[8];
  const float* q_w          = (const float*)d_in[9];
  const float* k_w          = (const float*)d_in[10];
  const float* v_w          = (const float*)d_in[11];
  const float* cross_proj_w = (const float*)d_in[12];
  const float* cross_proj_b = (const float*)d_in[13];
  const float* fc1_w        = (const float*)d_in[14];
  const float* fc1_b        = (const float*)d_in[15];
  const float* fc2_w        = (const float*)d_in[16];
  const float* fc2_b        = (const float*)d_in[17];
  const float* ln1_w        = (const float*)d_in[18];
  const float* ln1_b        = (const float*)d_in[19];
  const float* ln2_w        = (const float*)d_in[20];
  const float* ln2_b        = (const float*)d_in[21];
  const float* ln3_w        = (const float*)d_in[22];
  const float* ln3_b        = (const float*)d_in[23];
  const float* lny_w        = (const float*)d_in[24];
  const float* lny_b        = (const float*)d_in[25];
  float* out = (float*)d_out;

  char* ws = (char*)d_ws;
  size_t off = 0;
  auto alloc = [&](size_t bytes) -> char* {
    char* p = ws + off; off += (bytes + 255) & ~(size_t)255; return p;
  };
  u16* wb_qkv   = (u16*)alloc((size_t)2304*768*2);
  u16* wb_aproj = (u16*)alloc((size_t)768*768*2);
  u16* wb_q     = (u16*)alloc((size_t)768*768*2);
  u16* wb_k     = (u16*)alloc((size_t)768*768*2);
  u16* wb_v     = (u16*)alloc((size_t)768*768*2);
  u16* wb_cproj = (u16*)alloc((size_t)768*768*2);
  u16* wb_fc1   = (u16*)alloc((size_t)3072*768*2);
  u16* wb_fc2   = (u16*)alloc((size_t)768*3072*2);
  float* x_ws   = (float*)alloc((size_t)ROWS*CD*4);
  u16* hbuf     = (u16*)alloc((size_t)ROWS*CD*2);
  u16* ynbuf    = (u16*)alloc((size_t)ROWS*CD*2);
  u16* o_self   = (u16*)alloc((size_t)ROWS*CD*2);
  u16* qs       = (u16*)alloc((size_t)ROWS*CD*2);
  u16* ks       = (u16*)alloc((size_t)ROWS*CD*2);
  u16* vs       = (u16*)alloc((size_t)ROWS*CD*2);
  u16* o_cross  = (u16*)alloc((size_t)CROSS_ROWS*CD*2);
  // time-disjoint union: qkv bf16 (28.9MB) / oproj f32 (77.1MB) / mid bf16 (38.5MB)
  char* un = alloc((size_t)CROSS_ROWS*CD*4);
  u16*   qkvbuf = (u16*)un;
  float* oproj  = (float*)un;
  u16*   mid    = (u16*)un;

  auto cast = [&](const float* src, u16* dst, int n){
    k_cast_bf16<<<(n + 255) / 256, 256, 0, stream>>>(src, dst, n);
  };
  cast(qkv_w,        wb_qkv,   2304*768);
  cast(attn_proj_w,  wb_aproj, 768*768);
  cast(q_w,          wb_q,     768*768);
  cast(k_w,          wb_k,     768*768);
  cast(v_w,          wb_v,     768*768);
  cast(cross_proj_w, wb_cproj, 768*768);
  cast(fc1_w,        wb_fc1,   3072*768);
  cast(fc2_w,        wb_fc2,   768*3072);

  // ---- self attention block ----
  k_ln_bf16<<<ROWS, 256, 0, stream>>>(xs, ln1_w, ln1_b, hbuf);
  k_gemm_bt<0><<<dim3(2304/128, ROWS/128), 256, 0, stream>>>(
      hbuf, wb_qkv, nullptr, qkvbuf, nullptr, nullptr, ROWS, 2304, 768);
  k_attn<<<VBB * H_, 256, 0, stream>>>(qkvbuf, qkvbuf, qkvbuf, o_self, rel_ids, 0);
  k_gemm_bt<1><<<dim3(768/128, ROWS/128), 256, 0, stream>>>(
      o_self, wb_aproj, x_ws, nullptr, attn_proj_b, xs, ROWS, 768, 768);

  // ---- cross attention block ----
  k_ln_bf16<<<ROWS, 256, 0, stream>>>(x_ws, ln2_w, ln2_b, hbuf);
  k_ln_bf16<<<ROWS, 256, 0, stream>>>(ys, lny_w, lny_b, ynbuf);
  k_gemm_bt<0><<<dim3(768/128, ROWS/128), 256, 0, stream>>>(
      hbuf, wb_q, nullptr, qs, nullptr, nullptr, ROWS, 768, 768);
  k_gemm_bt<0><<<dim3(768/128, ROWS/128), 256, 0, stream>>>(
      ynbuf, wb_k, nullptr, ks, nullptr, nullptr, ROWS, 768, 768);
  k_gemm_bt<0><<<dim3(768/128, ROWS/128), 256, 0, stream>>>(
      ynbuf, wb_v, nullptr, vs, nullptr, nullptr, ROWS, 768, 768);
  k_attn<<<VX * MV * BB * H_, 256, 0, stream>>>(qs, ks, vs, o_cross, rel_ids, 1);
  k_gemm_bt<2><<<dim3(768/128, CROSS_ROWS/128), 256, 0, stream>>>(
      o_cross, wb_cproj, oproj, nullptr, cross_proj_b, nullptr, CROSS_ROWS, 768, 768);
  k_maxmerge<<<(ROWS * CD + 255) / 256, 256, 0, stream>>>(oproj, x_ws);

  // ---- MLP block ----
  k_ln_bf16<<<ROWS, 256, 0, stream>>>(x_ws, ln3_w, ln3_b, hbuf);
  k_gemm_bt<3><<<dim3(HIDD/128, ROWS/128), 256, 0, stream>>>(
      hbuf, wb_fc1, nullptr, mid, fc1_b, nullptr, ROWS, HIDD, 768);
  k_gemm_bt<1><<<dim3(768/128, ROWS/128), 256, 0, stream>>>(
      mid, wb_fc2, out, nullptr, fc2_b, x_ws, ROWS, 768, HIDD);
}

// Round 2
// 534.418 us; speedup vs baseline: 2.0703x; 2.0703x over previous
//
#include <hip/hip_runtime.h>
#include <hip/hip_bf16.h>
#include <stdint.h>
#include <math.h>

#define H_ 12
#define NQ 196
#define CD 768
#define HIDD 3072
#define VX 8
#define VY 8
#define BB 4
#define MV 4
#define VBB 32
#define ROWS 6272          // VBB*NQ
#define CROSS_ROWS 25088   // VX*MV*BB*NQ
#define ATT_SCALE 0.125f

typedef __attribute__((ext_vector_type(8))) short short8;
typedef __attribute__((ext_vector_type(4))) float f32x4;
typedef unsigned short u16;

__device__ __forceinline__ float bf2f(u16 u){
  union { unsigned int i; float f; } v; v.i = ((unsigned int)u) << 16; return v.f;
}
__device__ __forceinline__ u16 f2bf(float f){
  union { unsigned int i; float f; } v; v.f = f;
  return (u16)((v.i + 0x7fff + ((v.i >> 16) & 1)) >> 16);  // RNE
}

// ---------------- cast f32 -> bf16 ----------------
__global__ void k_cast_bf16(const float* __restrict__ in, u16* __restrict__ out, int n){
  int i = blockIdx.x * 256 + threadIdx.x;
  if (i < n) out[i] = f2bf(in[i]);
}

// ---------------- LayerNorm (f32 in, bf16 out), C=768 fixed ----------------
__global__ __launch_bounds__(256) void k_ln_bf16(const float* __restrict__ x,
    const float* __restrict__ w, const float* __restrict__ b,
    u16* __restrict__ out){
  const int row = blockIdx.x;
  const int tid = threadIdx.x;
  const float* xr = x + (size_t)row * CD;
  float v0 = xr[tid], v1 = xr[tid + 256], v2 = xr[tid + 512];
  float s  = v0 + v1 + v2;
  float s2 = v0*v0 + v1*v1 + v2*v2;
  __shared__ float red[8];
  const int lane = tid & 63, wid = tid >> 6;
  #pragma unroll
  for (int o = 32; o; o >>= 1){ s += __shfl_down(s, o); s2 += __shfl_down(s2, o); }
  if (lane == 0){ red[wid] = s; red[wid + 4] = s2; }
  __syncthreads();
  if (tid == 0){
    red[0] = red[0] + red[1] + red[2] + red[3];
    red[4] = red[4] + red[5] + red[6] + red[7];
  }
  __syncthreads();
  const float mu   = red[0] * (1.f/768.f);
  const float var  = red[4] * (1.f/768.f) - mu*mu;
  const float rstd = rsqrtf(var + 1e-5f);
  u16* orow = out + (size_t)row * CD;
  orow[tid]       = f2bf((v0 - mu)*rstd*w[tid]       + b[tid]);
  orow[tid + 256] = f2bf((v1 - mu)*rstd*w[tid + 256] + b[tid + 256]);
  orow[tid + 512] = f2bf((v2 - mu)*rstd*w[tid + 512] + b[tid + 512]);
}

// ---------------- bf16 MFMA GEMM: C = A(MxK) @ B(NxK)^T, m97 structure ----------------
// EPI: 0 = plain -> bf16 out; 1 = +bias +resid -> f32; 2 = +bias -> f32; 3 = +bias +GELU -> bf16
template<int EPI>
__global__ __launch_bounds__(256) void k_gemm_bt(
    const u16* __restrict__ A, const u16* __restrict__ B,
    float* __restrict__ Cf, u16* __restrict__ Cb,
    const float* __restrict__ bias, const float* __restrict__ resid,
    int M, int N, int K){
  __shared__ u16 As[128 * 64];
  __shared__ u16 Bs[128 * 64];
  const int tid  = threadIdx.x;
  const int lane = tid & 63;
  const int wave = tid >> 6;
  const int wr = wave >> 1, wc = wave & 1;
  const int m0 = blockIdx.y * 128, n0 = blockIdx.x * 128;

  f32x4 acc[4][4];
  #pragma unroll
  for (int i = 0; i < 4; i++)
    #pragma unroll
    for (int j = 0; j < 4; j++) acc[i][j] = (f32x4){0.f, 0.f, 0.f, 0.f};

  const int lrow = lane >> 3;        // 0..7
  const int lcol = (lane & 7) * 8;   // 0,8,..,56
  const u16* arow = A + (size_t)(m0 + wave*32 + lrow) * K + lcol;
  const u16* brow = B + (size_t)(n0 + wave*32 + lrow) * K + lcol;

  for (int k0 = 0; k0 < K; k0 += 64){
    #pragma unroll
    for (int i = 0; i < 4; i++){
      __builtin_amdgcn_global_load_lds(
        (const __attribute__((address_space(1))) void*)(arow + (size_t)i*8*K + k0),
        (__attribute__((address_space(3))) void*)(As + (wave*4 + i)*512),
        16, 0, 0);
      __builtin_amdgcn_global_load_lds(
        (const __attribute__((address_space(1))) void*)(brow + (size_t)i*8*K + k0),
        (__attribute__((address_space(3))) void*)(Bs + (wave*4 + i)*512),
        16, 0, 0);
    }
    __syncthreads();
    const u16* ab = As + (wr*64 + (lane & 15))*64 + (lane >> 4)*8;
    const u16* bb = Bs + (wc*64 + (lane & 15))*64 + (lane >> 4)*8;
    #pragma unroll
    for (int kk = 0; kk < 2; kk++){
      short8 af[4], bfr[4];
      #pragma unroll
      for (int f = 0; f < 4; f++){
        af[f]  = *(const short8*)(ab + f*1024 + kk*32);
        bfr[f] = *(const short8*)(bb + f*1024 + kk*32);
      }
      #pragma unroll
      for (int i = 0; i < 4; i++)
        #pragma unroll
        for (int j = 0; j < 4; j++)
          acc[i][j] = __builtin_amdgcn_mfma_f32_16x16x32_bf16(af[i], bfr[j], acc[i][j], 0, 0, 0);
    }
    __syncthreads();
  }

  #pragma unroll
  for (int i = 0; i < 4; i++){
    const int rb = m0 + wr*64 + i*16 + (lane >> 4)*4;
    #pragma unroll
    for (int j = 0; j < 4; j++){
      const int col = n0 + wc*64 + j*16 + (lane & 15);
      #pragma unroll
      for (int r = 0; r < 4; r++){
        const size_t idx = (size_t)(rb + r) * N + col;
        const float v = acc[i][j][r];
        if (EPI == 0){
          Cb[idx] = f2bf(v);
        } else if (EPI == 1){
          Cf[idx] = v + bias[col] + resid[idx];
        } else if (EPI == 2){
          Cf[idx] = v + bias[col];
        } else {
          float g = v + bias[col];
          g = 0.5f * g * (1.f + erff(g * 0.70710678118654752f));
          Cb[idx] = f2bf(g);
        }
      }
    }
  }
}

// ---------------- MFMA flash attention ----------------
// One block = one head-instance; 4 waves x 64 queries (padded to 256); keys tiled 32 (padded 224).
// Swapped operands: S^T = mfma(K, Q) so C col = query (lane&15); O^T = mfma(V^T, P^T).
// MODE 0: self (QKV packed, row stride 2304); MODE 1: cross (rel_ids gather on K/V).
template<int MODE>
__global__ __launch_bounds__(256) void k_attn_mfma(
    const u16* __restrict__ Qb, const u16* __restrict__ Kb, const u16* __restrict__ Vb,
    u16* __restrict__ Ob, const int* __restrict__ rel_ids){
  __shared__ u16 Kl[2048];       // [key 32][dh 64], 16B-slot swizzle: slot ^= (key&7)
  __shared__ u16 Vt[2048];       // [dh 64][key 32], 16B-slot swizzle: slot ^= ((dh>>3)&3)
  __shared__ u16 Pl[4][2048];    // per-wave [q 64][key 32], slot ^= (q&3)

  size_t qbase, kbase, vbase, obase;
  int qstr, kstr;
  if (MODE == 0){
    const int vb = blockIdx.x / H_, h = blockIdx.x % H_;
    qbase = (size_t)vb * NQ * 2304 + h * 64; qstr = 2304;
    kbase = qbase + 768; vbase = qbase + 1536; kstr = 2304;
    obase = (size_t)vb * NQ * CD + h * 64;
  } else {
    const int h = blockIdx.x % H_; int t = blockIdx.x / H_;
    const int b = t % BB; t /= BB;
    const int m = t % MV; const int vx = t / MV;
    const int rel = rel_ids[vx * MV + m];
    qbase = ((size_t)(vx * BB + b) * NQ) * CD + h * 64; qstr = CD;
    kbase = ((size_t)(rel * BB + b) * NQ) * CD + h * 64; kstr = CD;
    vbase = kbase;
    obase = ((size_t)((vx * MV + m) * BB + b) * NQ) * CD + h * 64;
  }

  const int tid  = threadIdx.x;
  const int lane = tid & 63;
  const int wave = tid >> 6;
  const int lq   = lane & 15;   // query-in-frag (C col)
  const int g    = lane >> 4;   // k-group

  // Q fragments: B-operand layout B[k=g*8+j][n=lq] = Q[qf*16+lq][ks*32+g*8+j]
  short8 qfrag[4][2];
  #pragma unroll
  for (int qf = 0; qf < 4; qf++){
    int qrow = wave*64 + qf*16 + lq; if (qrow > 195) qrow = 195;
    const u16* qp = Qb + qbase + (size_t)qrow * qstr + g*8;
    qfrag[qf][0] = *(const short8*)(qp);
    qfrag[qf][1] = *(const short8*)(qp + 32);
  }

  f32x4 oacc[4][4];
  #pragma unroll
  for (int i = 0; i < 4; i++)
    #pragma unroll
    for (int j = 0; j < 4; j++) oacc[i][j] = (f32x4){0.f,0.f,0.f,0.f};
  float m_[4], l_[4];
  #pragma unroll
  for (int i = 0; i < 4; i++){ m_[i] = -1e30f; l_[i] = 0.f; }

  const int skey = tid >> 3;        // staging: key 0..31
  const int sphys = tid & 7;        // physical 16B slot
  const int sslot = sphys ^ (skey & 7);
  const int vdh0 = (tid & 7) * 8;

  for (int t0 = 0; t0 < 224; t0 += 32){
    __syncthreads();
    {
      int kg = t0 + skey; if (kg > 195) kg = 195;
      __builtin_amdgcn_global_load_lds(
        (const __attribute__((address_space(1))) void*)(Kb + kbase + (size_t)kg*kstr + sslot*8),
        (__attribute__((address_space(3))) void*)(Kl + wave*512), 16, 0, 0);
      short8 vv = *(const short8*)(Vb + vbase + (size_t)kg*kstr + vdh0);
      #pragma unroll
      for (int j = 0; j < 8; j++){
        int dh = vdh0 + j;
        int ssw = (skey >> 3) ^ ((dh >> 3) & 3);
        Vt[dh*32 + ssw*8 + (skey & 7)] = (u16)vv[j];
      }
    }
    __syncthreads();

    // ---- S^T tile: 32 keys x 64 queries per wave ----
    f32x4 sacc[4][2];
    #pragma unroll
    for (int qf = 0; qf < 4; qf++)
      #pragma unroll
      for (int kf = 0; kf < 2; kf++) sacc[qf][kf] = (f32x4){0.f,0.f,0.f,0.f};
    #pragma unroll
    for (int kf = 0; kf < 2; kf++){
      const int key = kf*16 + lq;
      #pragma unroll
      for (int ks = 0; ks < 2; ks++){
        short8 kfrag = *(const short8*)(Kl + key*64 + (((ks<<2) + g) ^ (key & 7))*8);
        #pragma unroll
        for (int qf = 0; qf < 4; qf++)
          sacc[qf][kf] = __builtin_amdgcn_mfma_f32_16x16x32_bf16(kfrag, qfrag[qf][ks], sacc[qf][kf], 0, 0, 0);
      }
    }

    // ---- online softmax (query = lq, lane-local m/l) + P -> LDS ----
    #pragma unroll
    for (int qf = 0; qf < 4; qf++){
      float tv[8];
      #pragma unroll
      for (int kf = 0; kf < 2; kf++)
        #pragma unroll
        for (int r = 0; r < 4; r++){
          const int key = t0 + kf*16 + g*4 + r;
          const float s = sacc[qf][kf][r] * ATT_SCALE;
          tv[kf*4 + r] = (key < 196) ? s : -1e30f;
        }
      float tmax = tv[0];
      #pragma unroll
      for (int i = 1; i < 8; i++) tmax = fmaxf(tmax, tv[i]);
      tmax = fmaxf(tmax, __shfl_xor(tmax, 16));
      tmax = fmaxf(tmax, __shfl_xor(tmax, 32));
      const float mn  = fmaxf(m_[qf], tmax);
      const float rsc = __expf(m_[qf] - mn);
      m_[qf] = mn;
      float p[8], ps = 0.f;
      #pragma unroll
      for (int i = 0; i < 8; i++){ p[i] = __expf(tv[i] - mn); ps += p[i]; }
      ps += __shfl_xor(ps, 16);
      ps += __shfl_xor(ps, 32);
      l_[qf] = l_[qf]*rsc + ps;
      #pragma unroll
      for (int dhf = 0; dhf < 4; dhf++) oacc[qf][dhf] *= rsc;
      const int q = qf*16 + lq;
      #pragma unroll
      for (int kf = 0; kf < 2; kf++){
        const int key0 = kf*16 + g*4;
        const int ssw = (key0 >> 3) ^ (q & 3);
        u16* basep = Pl[wave] + q*32 + ssw*8 + (key0 & 7);
        unsigned int w0 = (unsigned)f2bf(p[kf*4])   | ((unsigned)f2bf(p[kf*4+1]) << 16);
        unsigned int w1 = (unsigned)f2bf(p[kf*4+2]) | ((unsigned)f2bf(p[kf*4+3]) << 16);
        *(unsigned int*)(basep)     = w0;
        *(unsigned int*)(basep + 2) = w1;
      }
    }

    // ---- O^T += mfma(V^T, P^T), K=32 covers the tile ----
    short8 vfrag[4], pfrag[4];
    #pragma unroll
    for (int dhf = 0; dhf < 4; dhf++){
      const int dh = dhf*16 + lq;
      const int ssw = g ^ ((dh >> 3) & 3);
      vfrag[dhf] = *(const short8*)(Vt + dh*32 + ssw*8);
    }
    #pragma unroll
    for (int qf = 0; qf < 4; qf++){
      const int q = qf*16 + lq;
      const int ssw = g ^ (q & 3);
      pfrag[qf] = *(const short8*)(Pl[wave] + q*32 + ssw*8);
      #pragma unroll
      for (int dhf = 0; dhf < 4; dhf++)
        oacc[qf][dhf] = __builtin_amdgcn_mfma_f32_16x16x32_bf16(vfrag[dhf], pfrag[qf], oacc[qf][dhf], 0, 0, 0);
    }
  }

  // ---- epilogue: divide by l (lane-local), store O[q][dh] ----
  #pragma unroll
  for (int qf = 0; qf < 4; qf++){
    const int qrow = wave*64 + qf*16 + lq;
    if (qrow < 196){
      const float inv = 1.f / l_[qf];
      u16* orow = Ob + obase + (size_t)qrow * CD;
      #pragma unroll
      for (int dhf = 0; dhf < 4; dhf++){
        uint2 pk;
        pk.x = (unsigned)f2bf(oacc[qf][dhf][0]*inv) | ((unsigned)f2bf(oacc[qf][dhf][1]*inv) << 16);
        pk.y = (unsigned)f2bf(oacc[qf][dhf][2]*inv) | ((unsigned)f2bf(oacc[qf][dhf][3]*inv) << 16);
        *(uint2*)(orow + dhf*16 + g*4) = pk;
      }
    }
  }
}

// ---------------- max over M + residual add ----------------
__global__ void k_maxmerge(const float* __restrict__ op, float* __restrict__ x){
  const int idx = blockIdx.x * 256 + threadIdx.x;
  if (idx >= VX * BB * NQ * CD) return;
  const int inner = idx % (NQ * CD);
  const int vb = idx / (NQ * CD);
  const int vx = vb >> 2, b = vb & 3;
  const size_t ms = (size_t)BB * NQ * CD;
  const size_t base = ((size_t)vx * MV * BB + b) * (NQ * CD) + inner;
  float v = op[base];
  v = fmaxf(v, op[base + ms]);
  v = fmaxf(v, op[base + 2 * ms]);
  v = fmaxf(v, op[base + 3 * ms]);
  x[idx] += v;
}

extern "C" void kernel_launch(void* const* d_in, const int* in_sizes, int n_in,
                              void* d_out, int out_size, void* d_ws, size_t ws_size,
                              hipStream_t stream){
  const float* xs           = (const float*)d_in[0];
  const float* ys           = (const float*)d_in[1];
  const int*   rel_ids      = (const int*)  d_in[4];
  const float* qkv_w        = (const float*)d_in[6];
  const float* attn_proj_w  = (const float*)d_in[7];
  const float* attn_proj_b  = (const float*)d_in[8];
  const float* q_w          = (const float*)d_in[9];
  const float* k_w          = (const float*)d_in[10];
  const float* v_w          = (const float*)d_in[11];
  const float* cross_proj_w = (const float*)d_in[12];
  const float* cross_proj_b = (const float*)d_in[13];
  const float* fc1_w        = (const float*)d_in[14];
  const float* fc1_b        = (const float*)d_in[15];
  const float* fc2_w        = (const float*)d_in[16];
  const float* fc2_b        = (const float*)d_in[17];
  const float* ln1_w        = (const float*)d_in[18];
  const float* ln1_b        = (const float*)d_in[19];
  const float* ln2_w        = (const float*)d_in[20];
  const float* ln2_b        = (const float*)d_in[21];
  const float* ln3_w        = (const float*)d_in[22];
  const float* ln3_b        = (const float*)d_in[23];
  const float* lny_w        = (const float*)d_in[24];
  const float* lny_b        = (const float*)d_in[25];
  float* out = (float*)d_out;

  char* ws = (char*)d_ws;
  size_t off = 0;
  auto alloc = [&](size_t bytes) -> char* {
    char* p = ws + off; off += (bytes + 255) & ~(size_t)255; return p;
  };
  u16* wb_qkv   = (u16*)alloc((size_t)2304*768*2);
  u16* wb_aproj = (u16*)alloc((size_t)768*768*2);
  u16* wb_q     = (u16*)alloc((size_t)768*768*2);
  u16* wb_k     = (u16*)alloc((size_t)768*768*2);
  u16* wb_v     = (u16*)alloc((size_t)768*768*2);
  u16* wb_cproj = (u16*)alloc((size_t)768*768*2);
  u16* wb_fc1   = (u16*)alloc((size_t)3072*768*2);
  u16* wb_fc2   = (u16*)alloc((size_t)768*3072*2);
  float* x_ws   = (float*)alloc((size_t)ROWS*CD*4);
  u16* hbuf     = (u16*)alloc((size_t)ROWS*CD*2);
  u16* ynbuf    = (u16*)alloc((size_t)ROWS*CD*2);
  u16* o_self   = (u16*)alloc((size_t)ROWS*CD*2);
  u16* qs       = (u16*)alloc((size_t)ROWS*CD*2);
  u16* ks       = (u16*)alloc((size_t)ROWS*CD*2);
  u16* vs       = (u16*)alloc((size_t)ROWS*CD*2);
  u16* o_cross  = (u16*)alloc((size_t)CROSS_ROWS*CD*2);
  // time-disjoint union: qkv bf16 (28.9MB) / oproj f32 (77.1MB) / mid bf16 (38.5MB)
  char* un = alloc((size_t)CROSS_ROWS*CD*4);
  u16*   qkvbuf = (u16*)un;
  float* oproj  = (float*)un;
  u16*   mid    = (u16*)un;

  auto cast = [&](const float* src, u16* dst, int n){
    k_cast_bf16<<<(n + 255) / 256, 256, 0, stream>>>(src, dst, n);
  };
  cast(qkv_w,        wb_qkv,   2304*768);
  cast(attn_proj_w,  wb_aproj, 768*768);
  cast(q_w,          wb_q,     768*768);
  cast(k_w,          wb_k,     768*768);
  cast(v_w,          wb_v,     768*768);
  cast(cross_proj_w, wb_cproj, 768*768);
  cast(fc1_w,        wb_fc1,   3072*768);
  cast(fc2_w,        wb_fc2,   768*3072);

  // ---- self attention block ----
  k_ln_bf16<<<ROWS, 256, 0, stream>>>(xs, ln1_w, ln1_b, hbuf);
  k_gemm_bt<0><<<dim3(2304/128, ROWS/128), 256, 0, stream>>>(
      hbuf, wb_qkv, nullptr, qkvbuf, nullptr, nullptr, ROWS, 2304, 768);
  k_attn_mfma<0><<<VBB * H_, 256, 0, stream>>>(qkvbuf, qkvbuf, qkvbuf, o_self, rel_ids);
  k_gemm_bt<1><<<dim3(768/128, ROWS/128), 256, 0, stream>>>(
      o_self, wb_aproj, x_ws, nullptr, attn_proj_b, xs, ROWS, 768, 768);

  // ---- cross attention block ----
  k_ln_bf16<<<ROWS, 256, 0, stream>>>(x_ws, ln2_w, ln2_b, hbuf);
  k_ln_bf16<<<ROWS, 256, 0, stream>>>(ys, lny_w, lny_b, ynbuf);
  k_gemm_bt<0><<<dim3(768/128, ROWS/128), 256, 0, stream>>>(
      hbuf, wb_q, nullptr, qs, nullptr, nullptr, ROWS, 768, 768);
  k_gemm_bt<0><<<dim3(768/128, ROWS/128), 256, 0, stream>>>(
      ynbuf, wb_k, nullptr, ks, nullptr, nullptr, ROWS, 768, 768);
  k_gemm_bt<0><<<dim3(768/128, ROWS/128), 256, 0, stream>>>(
      ynbuf, wb_v, nullptr, vs, nullptr, nullptr, ROWS, 768, 768);
  k_attn_mfma<1><<<VX * MV * BB * H_, 256, 0, stream>>>(qs, ks, vs, o_cross, rel_ids);
  k_gemm_bt<2><<<dim3(768/128, CROSS_ROWS/128), 256, 0, stream>>>(
      o_cross, wb_cproj, oproj, nullptr, cross_proj_b, nullptr, CROSS_ROWS, 768, 768);
  k_maxmerge<<<(ROWS * CD + 255) / 256, 256, 0, stream>>>(oproj, x_ws);

  // ---- MLP block ----
  k_ln_bf16<<<ROWS, 256, 0, stream>>>(x_ws, ln3_w, ln3_b, hbuf);
  k_gemm_bt<3><<<dim3(HIDD/128, ROWS/128), 256, 0, stream>>>(
      hbuf, wb_fc1, nullptr, mid, fc1_b, nullptr, ROWS, HIDD, 768);
  k_gemm_bt<1><<<dim3(768/128, ROWS/128), 256, 0, stream>>>(
      mid, wb_fc2, out, nullptr, fc2_b, x_ws, ROWS, 768, HIDD);
}